// Round 6
// baseline (3230.031 us; speedup 1.0000x reference)
//
#include <hip/hip_runtime.h>
#include <stdint.h>
#include <stddef.h>

// ---------- types / helpers ----------
typedef __attribute__((ext_vector_type(8))) short  short8;   // 8 bf16 (4 VGPRs)
typedef __attribute__((ext_vector_type(4))) float  floatx4;  // MFMA acc
typedef __attribute__((ext_vector_type(4))) unsigned int uintx4;
typedef unsigned long long u64;

#define SENT 0xAAAAAAAAAAAAAAAAull   // ws poison pattern = our sentinel

static __device__ __forceinline__ float b2f(uint16_t h) {
  union { uint32_t u; float f; } v; v.u = ((uint32_t)h) << 16; return v.f;
}
static __device__ __forceinline__ uint16_t f2b(float f) {
  union { float f; uint32_t u; } v; v.f = f;
  uint32_t u = v.u;
  uint32_t r = u + 0x7FFFu + ((u >> 16) & 1u);   // RNE
  return (uint16_t)(r >> 16);
}
static __device__ __forceinline__ float sigm(float x)  { return 1.0f / (1.0f + __expf(-x)); }
static __device__ __forceinline__ float tanh_f(float x){ return 1.0f - 2.0f / (1.0f + __expf(2.0f * x)); }

static __device__ __forceinline__ floatx4 mfma16(short8 a, short8 b, floatx4 c) {
  return __builtin_amdgcn_mfma_f32_16x16x32_bf16(a, b, c, 0, 0, 0);
}
static __device__ __forceinline__ short8 cvt8(const float* p) {
  short8 r;
  #pragma unroll
  for (int i = 0; i < 8; ++i) r[i] = (short)f2b(p[i]);
  return r;
}
// ---- slow path: agent-scope relaxed atomics (proven rounds 2/4/5) ----
static __device__ __forceinline__ u64 ld_h64(const u64* p) {
  return __hip_atomic_load(p, __ATOMIC_RELAXED, __HIP_MEMORY_SCOPE_AGENT);
}
static __device__ __forceinline__ void st_h64(uint16_t* p, u64 v) {
  __hip_atomic_store((u64*)p, v, __ATOMIC_RELAXED, __HIP_MEMORY_SCOPE_AGENT);
}
// ---- fast path: sc0 (bypass L1, stop at XCD L2). Stale reads can only
// return the sentinel (line only ever holds sentinel or final data), so a
// cross-XCD placement degrades to the slow path — never wrong data. ----
static __device__ __forceinline__ void st64_sc0(uint16_t* p, u64 v) {
  asm volatile("global_store_dwordx2 %0, %1, off sc0" : : "v"(p), "v"(v) : "memory");
}
static __device__ __forceinline__ void ld8_sc0(const u64* p, u64* o) {
  uintx4 a, b, c, d;
  asm volatile(
    "global_load_dwordx4 %0, %4, off sc0\n\t"
    "global_load_dwordx4 %1, %5, off sc0\n\t"
    "global_load_dwordx4 %2, %6, off sc0\n\t"
    "global_load_dwordx4 %3, %7, off sc0\n\t"
    "s_waitcnt vmcnt(0)"
    : "=&v"(a), "=&v"(b), "=&v"(c), "=&v"(d)
    : "v"(p), "v"(p + 2), "v"(p + 4), "v"(p + 6)
    : "memory");
  o[0] = ((u64)a.y << 32) | a.x;  o[1] = ((u64)a.w << 32) | a.z;
  o[2] = ((u64)b.y << 32) | b.x;  o[3] = ((u64)b.w << 32) | b.z;
  o[4] = ((u64)c.y << 32) | c.x;  o[5] = ((u64)c.w << 32) | c.z;
  o[6] = ((u64)d.y << 32) | d.x;  o[7] = ((u64)d.w << 32) | d.z;
}
// dual-path poll: fast (sc0/L2) first, merge slow (agent) per word
static __device__ __forceinline__ void poll8_dual(const u64* pf, const u64* ps, u64* o) {
  #pragma unroll
  for (int i = 0; i < 8; ++i) o[i] = SENT;
  for (;;) {
    u64 f[8];
    ld8_sc0(pf, f);
    bool ok = true;
    #pragma unroll
    for (int i = 0; i < 8; ++i) {
      if (o[i] == SENT) o[i] = f[i];
      ok &= (o[i] != SENT);
    }
    if (ok) return;
    ok = true;
    #pragma unroll
    for (int i = 0; i < 8; ++i) {
      if (o[i] == SENT) o[i] = ld_h64(ps + i);
      ok &= (o[i] != SENT);
    }
    if (ok) return;
    __builtin_amdgcn_s_sleep(1);
  }
}

#define H 256
#define FH 1024
#define BATCH 32
#define TSEQ 512
#define DSTEPS 64
#define ERING 8          // encoder h-slot ring depth

// =====================================================================
// Phase A GEMM (unchanged — correct since round 2)
// =====================================================================
__global__ __launch_bounds__(256) void gemm_xw(
    const float* __restrict__ A, const float* __restrict__ W,
    const float* __restrict__ bias, void* __restrict__ Cout, int out_f32)
{
  const int K = 1024, N = 1024;
  __shared__ uint16_t Ah[64 * 40], Al[64 * 40];
  __shared__ uint16_t Wh[64 * 40], Wl[64 * 40];
  const int m0 = blockIdx.x * 64;
  const int n0 = blockIdx.y * 64;
  const int tid = threadIdx.x;
  const int lane = tid & 63, w = tid >> 6;
  const int wm = w & 1, wn = w >> 1;
  const int l15 = lane & 15, q4 = lane >> 4;
  const int ldrow = tid >> 2, ldk = (tid & 3) * 8;

  floatx4 acc[2][2];
  for (int i = 0; i < 2; ++i) for (int j = 0; j < 2; ++j) acc[i][j] = (floatx4){0.f,0.f,0.f,0.f};

  for (int kb = 0; kb < K; kb += 32) {
    float aa[8], ww[8];
    {
      const float4* ap = (const float4*)(A + (size_t)(m0 + ldrow) * K + kb + ldk);
      const float4* wp = (const float4*)(W + (size_t)(n0 + ldrow) * K + kb + ldk);
      *(float4*)(aa) = ap[0]; *(float4*)(aa + 4) = ap[1];
      *(float4*)(ww) = wp[0]; *(float4*)(ww + 4) = wp[1];
    }
    short8 ah, al, wh, wl;
    #pragma unroll
    for (int i = 0; i < 8; ++i) {
      uint16_t h = f2b(aa[i]); ah[i] = (short)h; al[i] = (short)f2b(aa[i] - b2f(h));
      uint16_t g = f2b(ww[i]); wh[i] = (short)g; wl[i] = (short)f2b(ww[i] - b2f(g));
    }
    __syncthreads();
    *(short8*)(Ah + ldrow * 40 + ldk) = ah;
    *(short8*)(Al + ldrow * 40 + ldk) = al;
    *(short8*)(Wh + ldrow * 40 + ldk) = wh;
    *(short8*)(Wl + ldrow * 40 + ldk) = wl;
    __syncthreads();
    short8 afh[2], afl[2], bfh[2], bfl[2];
    #pragma unroll
    for (int mt = 0; mt < 2; ++mt) {
      afh[mt] = *(const short8*)(Ah + (wm * 32 + mt * 16 + l15) * 40 + q4 * 8);
      afl[mt] = *(const short8*)(Al + (wm * 32 + mt * 16 + l15) * 40 + q4 * 8);
    }
    #pragma unroll
    for (int nt = 0; nt < 2; ++nt) {
      bfh[nt] = *(const short8*)(Wh + (wn * 32 + nt * 16 + l15) * 40 + q4 * 8);
      bfl[nt] = *(const short8*)(Wl + (wn * 32 + nt * 16 + l15) * 40 + q4 * 8);
    }
    #pragma unroll
    for (int mt = 0; mt < 2; ++mt)
      #pragma unroll
      for (int nt = 0; nt < 2; ++nt) {
        acc[mt][nt] = mfma16(afh[mt], bfh[nt], acc[mt][nt]);
        acc[mt][nt] = mfma16(afh[mt], bfl[nt], acc[mt][nt]);
        acc[mt][nt] = mfma16(afl[mt], bfh[nt], acc[mt][nt]);
      }
  }
  #pragma unroll
  for (int mt = 0; mt < 2; ++mt)
    #pragma unroll
    for (int nt = 0; nt < 2; ++nt) {
      const int col = n0 + wn * 32 + nt * 16 + l15;
      const float bv = bias[col];
      #pragma unroll
      for (int r = 0; r < 4; ++r) {
        const int row = m0 + wm * 32 + mt * 16 + q4 * 4 + r;
        const float v = acc[mt][nt][r] + bv;
        if (out_f32) ((float*)Cout)[(size_t)row * N + col] = v;
        else         ((uint16_t*)Cout)[(size_t)row * N + col] = f2b(v);
      }
    }
}

// =====================================================================
// Phase B: encoder recurrence. 128 WGs launched; active iff
// (blockIdx%8)<2 && (blockIdx/8)<8: d = blockIdx%8, q = blockIdx/8.
// Under round-robin block->XCD dispatch each direction's 8 WGs share one
// XCD, so the sc0 fast path resolves in-L2; otherwise slow path covers.
// Data-is-the-flag, 8-deep ring, consumer re-poisons slot s-2 (both copies).
// =====================================================================
__global__ __launch_bounds__(256, 1) void enc_rnn(
    const void* __restrict__ XgF, const void* __restrict__ XgB, int xg_f32,
    const float* __restrict__ WhhF, const float* __restrict__ WhhB,
    uint16_t* __restrict__ hslF,      // [2][ERING][32][256] bf16, poisoned (fast)
    uint16_t* __restrict__ hslS,      // [2][ERING][32][256] bf16, poisoned (slow)
    uint16_t* __restrict__ hfin, float* __restrict__ cfin)
{
  const int res = blockIdx.x & 7, k = blockIdx.x >> 3;
  if (res >= 2 || k >= 8) return;
  const int d = res, q = k;
  const void*  Xg  = d ? XgB : XgF;
  const float* Whh = d ? WhhB : WhhF;
  uint16_t* hf = hslF + d * (ERING * BATCH * H);
  uint16_t* hs = hslS + d * (ERING * BATCH * H);
  const int jOff = q * 32;
  const int tid = threadIdx.x, lane = tid & 63, w = tid >> 6;
  const int tt = w & 1, nt = w >> 1, l15 = lane & 15, q4 = lane >> 4;
  const int b = nt * 16 + l15;
  const int jg = jOff + tt * 16 + q4 * 4;

  __shared__ uint16_t hS[2][32 * 264];
  __shared__ float    xgS[2][32 * 132];

  short8 Af[4][8];
  #pragma unroll
  for (int g = 0; g < 4; ++g) {
    const int grow = g * H + jOff + tt * 16 + l15;
    #pragma unroll
    for (int ks = 0; ks < 8; ++ks)
      Af[g][ks] = cvt8(Whh + (size_t)grow * H + ks * 32 + q4 * 8);
  }
  for (int i = tid; i < 32 * 264; i += 256) hS[0][i] = 0;   // h_0 = 0

  float cc[4] = {0.f, 0.f, 0.f, 0.f};
  union HV { uint16_t u16[4]; u64 v; } hv; hv.v = 0ull;
  const int rb = tid >> 3, seg = tid & 7;
  const int cp = seg * 16;
  const int gge = cp >> 5, jj = cp & 31;

  for (int s = 0; s < TSEQ; ++s) {
    const int t = d ? (TSEQ - 1 - s) : s;
    const int p = s & 1;
    // stage this step's Xg slice early
    float xv[16];
    {
      const size_t base = (size_t)(t * BATCH + rb) * FH + gge * H + jOff + jj;
      if (xg_f32) {
        const float4* xs = (const float4*)((const float*)Xg + base);
        *(float4*)(xv) = xs[0]; *(float4*)(xv + 4) = xs[1];
        *(float4*)(xv + 8) = xs[2]; *(float4*)(xv + 12) = xs[3];
      } else {
        const uint16_t* xs = (const uint16_t*)Xg + base;
        #pragma unroll
        for (int i = 0; i < 16; ++i) xv[i] = b2f(xs[i]);
      }
    }

    if (s > 0) {
      u64 tmp[8];
      const size_t soff = (size_t)((s - 1) & (ERING - 1)) * (BATCH * H) + rb * H + seg * 32;
      poll8_dual((const u64*)(hf + soff), (const u64*)(hs + soff), tmp);
      #pragma unroll
      for (int i = 0; i < 8; ++i)
        *(u64*)(hS[p] + rb * 264 + seg * 32 + i * 4) = tmp[i];
    }
    if (s >= 2) {  // re-poison own slice of slot s-2 (both copies)
      const size_t poff = (size_t)((s - 2) & (ERING - 1)) * (BATCH * H) + b * H + jg;
      st64_sc0(hf + poff, SENT);
      st_h64(hs + poff, SENT);
    }
    #pragma unroll
    for (int i = 0; i < 16; ++i) xgS[p][rb * 132 + cp + i] = xv[i];
    __syncthreads();

    floatx4 a0 = {0.f,0.f,0.f,0.f}, a1 = a0, a2 = a0, a3 = a0;
    #pragma unroll
    for (int ks = 0; ks < 8; ++ks) {
      short8 bfv = *(const short8*)(hS[p] + b * 264 + ks * 32 + q4 * 8);
      a0 = mfma16(Af[0][ks], bfv, a0);
      a1 = mfma16(Af[1][ks], bfv, a1);
      a2 = mfma16(Af[2][ks], bfv, a2);
      a3 = mfma16(Af[3][ks], bfv, a3);
    }
    #pragma unroll
    for (int r = 0; r < 4; ++r) {
      const int jl = tt * 16 + q4 * 4 + r;
      const float gi = a0[r] + xgS[p][b * 132 +      jl];
      const float gf = a1[r] + xgS[p][b * 132 + 32 + jl];
      const float gc = a2[r] + xgS[p][b * 132 + 64 + jl];
      const float go = a3[r] + xgS[p][b * 132 + 96 + jl];
      const float cn2 = sigm(gf) * cc[r] + sigm(gi) * tanh_f(gc);
      cc[r] = cn2;
      hv.u16[r] = f2b(sigm(go) * tanh_f(cn2));
    }
    const size_t woff = (size_t)(s & (ERING - 1)) * (BATCH * H) + b * H + jg;
    st64_sc0(hf + woff, hv.v);
    st_h64(hs + woff, hv.v);
  }
  #pragma unroll
  for (int r = 0; r < 4; ++r) {
    hfin[d * (BATCH * H) + b * H + jg + r] = hv.u16[r];   // kernel boundary
    cfin[d * (BATCH * H) + b * H + jg + r] = cc[r];
  }
}

// =====================================================================
// Phase C: decoder. 128 WGs; active iff (blockIdx%8)==0 && (blockIdx/8)<16
// (all 16 presumed on one XCD): L = k>>3, q = k&7. Write-once dual slots.
// =====================================================================
__global__ __launch_bounds__(256, 1) void dec_rnn(
    const float* __restrict__ Wih0, const float* __restrict__ Whh0, const float* __restrict__ bb0,
    const float* __restrict__ Wih1, const float* __restrict__ Whh1, const float* __restrict__ bb1,
    const uint16_t* __restrict__ hfin, const float* __restrict__ cfin,
    uint16_t* __restrict__ h0F, uint16_t* __restrict__ h0S,
    uint16_t* __restrict__ h1F, uint16_t* __restrict__ h1S,
    float*    __restrict__ h1f)      // [64][32][256] f32 (plain)
{
  const int res = blockIdx.x & 7, k = blockIdx.x >> 3;
  if (res != 0 || k >= 16) return;
  const int L = k >> 3, q = k & 7;
  const float* Wih = L ? Wih1 : Wih0;
  const float* Whh = L ? Whh1 : Whh0;
  const float* bs  = L ? bb1 : bb0;
  const int jOff = q * 32;
  const int tid = threadIdx.x, lane = tid & 63, w = tid >> 6;
  const int tt = w & 1, nt = w >> 1, l15 = lane & 15, q4 = lane >> 4;
  const int b = nt * 16 + l15;
  const int jg = jOff + tt * 16 + q4 * 4;

  __shared__ uint16_t xhS[2][32 * 528];

  short8 Af[4][16];
  #pragma unroll
  for (int g = 0; g < 4; ++g) {
    const int grow = g * H + jOff + tt * 16 + l15;
    #pragma unroll
    for (int ks = 0; ks < 8; ++ks) {
      Af[g][ks]     = cvt8(Wih + (size_t)grow * H + ks * 32 + q4 * 8);
      Af[g][8 + ks] = cvt8(Whh + (size_t)grow * H + ks * 32 + q4 * 8);
    }
  }
  float brg[4][4];
  #pragma unroll
  for (int g = 0; g < 4; ++g)
    #pragma unroll
    for (int r = 0; r < 4; ++r)
      brg[g][r] = bs[g * H + jOff + tt * 16 + q4 * 4 + r];

  float cc[4];
  #pragma unroll
  for (int r = 0; r < 4; ++r) cc[r] = cfin[L * (BATCH * H) + b * H + jg + r];

  const int rb = tid >> 3, seg = tid & 7;
  const size_t off = (size_t)rb * H + seg * 32;
  union HV { uint16_t u16[4]; u64 v; } hv; hv.v = 0ull;

  for (int t = 0; t < DSTEPS; ++t) {
    const int p = t & 1;
    u64 tx[8], th[8];
    // own-layer previous h (early dependency)
    if (t == 0) {
      const u64* ph = (const u64*)(hfin + L * (BATCH * H) + off);
      #pragma unroll
      for (int i = 0; i < 8; ++i) th[i] = ph[i];       // plain, kernel boundary
    } else {
      const size_t so = (size_t)(t - 1) * (BATCH * H) + off;
      poll8_dual((const u64*)((L ? h1F : h0F) + so),
                 (const u64*)((L ? h1S : h0S) + so), th);
    }
    // cross-layer x (late dependency)
    if (L == 0) {
      if (t == 0) {
        #pragma unroll
        for (int i = 0; i < 8; ++i) tx[i] = 0ull;
      } else {
        const size_t so = (size_t)(t - 1) * (BATCH * H) + off;
        poll8_dual((const u64*)(h1F + so), (const u64*)(h1S + so), tx);
      }
    } else {
      const size_t so = (size_t)t * (BATCH * H) + off;
      poll8_dual((const u64*)(h0F + so), (const u64*)(h0S + so), tx);
    }
    #pragma unroll
    for (int i = 0; i < 8; ++i) {
      *(u64*)(xhS[p] + rb * 528 + seg * 32 + i * 4) = tx[i];
      *(u64*)(xhS[p] + rb * 528 + 256 + seg * 32 + i * 4) = th[i];
    }
    __syncthreads();

    floatx4 a0 = {0.f,0.f,0.f,0.f}, a1 = a0, a2 = a0, a3 = a0;
    #pragma unroll
    for (int ks = 0; ks < 16; ++ks) {
      short8 bfv = *(const short8*)(xhS[p] + b * 528 + ks * 32 + q4 * 8);
      a0 = mfma16(Af[0][ks], bfv, a0);
      a1 = mfma16(Af[1][ks], bfv, a1);
      a2 = mfma16(Af[2][ks], bfv, a2);
      a3 = mfma16(Af[3][ks], bfv, a3);
    }
    float hval[4];
    #pragma unroll
    for (int r = 0; r < 4; ++r) {
      const float gi = a0[r] + brg[0][r];
      const float gf = a1[r] + brg[1][r];
      const float gc = a2[r] + brg[2][r];
      const float go = a3[r] + brg[3][r];
      const float cn2 = sigm(gf) * cc[r] + sigm(gi) * tanh_f(gc);
      cc[r] = cn2;
      hval[r] = sigm(go) * tanh_f(cn2);
      hv.u16[r] = f2b(hval[r]);
    }
    const size_t wo = (size_t)t * (BATCH * H) + b * H + jg;
    st64_sc0((L ? h1F : h0F) + wo, hv.v);
    st_h64((L ? h1S : h0S) + wo, hv.v);
    if (L == 1) {
      float* df = h1f + (size_t)t * (BATCH * H) + b * H + jg;
      #pragma unroll
      for (int r = 0; r < 4; ++r) df[r] = hval[r];
    }
  }
}

// =====================================================================
// Phase D
// =====================================================================
__global__ __launch_bounds__(256) void out_proj(
    const float* __restrict__ h1f, const float* __restrict__ linW,
    const float* __restrict__ linb, float* __restrict__ out)
{
  const int idx = blockIdx.x * 256 + threadIdx.x;
  if (idx >= DSTEPS * BATCH * 3) return;
  const int v = idx % 3;
  const int tb = idx / 3;
  const float* hrow = h1f + (size_t)tb * H;
  const float* wrow = linW + (size_t)v * H;
  float s = linb[v];
  for (int k = 0; k < H; ++k) s += hrow[k] * wrow[k];
  out[idx] = s;
}

// =====================================================================
extern "C" void kernel_launch(void* const* d_in, const int* in_sizes, int n_in,
                              void* d_out, int out_size, void* d_ws, size_t ws_size,
                              hipStream_t stream) {
  (void)in_sizes; (void)n_in; (void)out_size;
  const float* cnn   = (const float*)d_in[0];
  const float* WihF  = (const float*)d_in[1];
  const float* WhhF  = (const float*)d_in[2];
  const float* bF    = (const float*)d_in[3];
  const float* WihB  = (const float*)d_in[4];
  const float* WhhB  = (const float*)d_in[5];
  const float* bB    = (const float*)d_in[6];
  const float* Wih0  = (const float*)d_in[7];
  const float* Whh0  = (const float*)d_in[8];
  const float* b0    = (const float*)d_in[9];
  const float* Wih1  = (const float*)d_in[10];
  const float* Whh1  = (const float*)d_in[11];
  const float* b1    = (const float*)d_in[12];
  const float* linW  = (const float*)d_in[13];
  const float* linb  = (const float*)d_in[14];

  const size_t XG_ELEMS = (size_t)TSEQ * BATCH * FH;   // 16 Mi elems / dir
  // tail region: encFast 262144 | encSlow 262144 | hfin 32768 | cfin 65536
  const size_t SMALL = 622592;
  const int xg_f32 = (ws_size >= 2 * XG_ELEMS * 4 + SMALL) ? 1 : 0;
  const size_t S = XG_ELEMS * (xg_f32 ? 4 : 2);

  uint8_t* ws = (uint8_t*)d_ws;
  void*     XgF    = (void*)(ws);
  void*     XgB    = (void*)(ws + S);
  float*    h1f    = (float*)(ws + S);                 // overlaps XgB (dead after enc)
  uint8_t*  base   = ws + 2 * S;
  uint16_t* hslF   = (uint16_t*)(base);                // 262144
  uint16_t* hslS   = (uint16_t*)(base + 262144);       // 262144
  uint16_t* hfin   = (uint16_t*)(base + 524288);       // 32768
  float*    cfin   = (float*)(base + 557056);          // 65536 (end 622592)
  // decoder slots overlap XgF (dead after enc); poisoned mid-stream
  uint16_t* h0F = (uint16_t*)(ws);
  uint16_t* h0S = (uint16_t*)(ws + 1048576);
  uint16_t* h1F = (uint16_t*)(ws + 2097152);
  uint16_t* h1S = (uint16_t*)(ws + 3145728);

  hipMemsetAsync(base, 0xAA, 524288, stream);          // enc slots (fast+slow)

  gemm_xw<<<dim3(256, 16), 256, 0, stream>>>(cnn, WihF, bF, XgF, xg_f32);
  gemm_xw<<<dim3(256, 16), 256, 0, stream>>>(cnn, WihB, bB, XgB, xg_f32);
  enc_rnn<<<128, 256, 0, stream>>>(XgF, XgB, xg_f32, WhhF, WhhB,
                                   hslF, hslS, hfin, cfin);
  hipMemsetAsync(ws, 0xAA, 4194304, stream);           // dec slots (XgF now dead)
  dec_rnn<<<128, 256, 0, stream>>>(Wih0, Whh0, b0, Wih1, Whh1, b1,
                                   hfin, cfin, h0F, h0S, h1F, h1S, h1f);
  out_proj<<<24, 256, 0, stream>>>(h1f, linW, linb, (float*)d_out);
}

// Round 8
// 2619.884 us; speedup vs baseline: 1.2329x; 1.2329x over previous
//
#include <hip/hip_runtime.h>
#include <stdint.h>
#include <stddef.h>

// ---------- types / helpers ----------
typedef __attribute__((ext_vector_type(8))) short  short8;   // 8 bf16 (4 VGPRs)
typedef __attribute__((ext_vector_type(4))) float  floatx4;  // MFMA acc
typedef unsigned long long u64;

#define SENT 0xAAAAAAAAAAAAAAAAull   // ws poison pattern = our sentinel

static __device__ __forceinline__ float b2f(uint16_t h) {
  union { uint32_t u; float f; } v; v.u = ((uint32_t)h) << 16; return v.f;
}
static __device__ __forceinline__ uint16_t f2b(float f) {
  union { float f; uint32_t u; } v; v.f = f;
  uint32_t u = v.u;
  uint32_t r = u + 0x7FFFu + ((u >> 16) & 1u);   // RNE
  return (uint16_t)(r >> 16);
}
static __device__ __forceinline__ float sigm(float x)  { return 1.0f / (1.0f + __expf(-x)); }
static __device__ __forceinline__ float tanh_f(float x){ return 1.0f - 2.0f / (1.0f + __expf(2.0f * x)); }

static __device__ __forceinline__ floatx4 mfma16(short8 a, short8 b, floatx4 c) {
  return __builtin_amdgcn_mfma_f32_16x16x32_bf16(a, b, c, 0, 0, 0);
}
static __device__ __forceinline__ short8 cvt8(const float* p) {
  short8 r;
  #pragma unroll
  for (int i = 0; i < 8; ++i) r[i] = (short)f2b(p[i]);
  return r;
}
// agent-scope primitives (proven rounds 2/4/5)
static __device__ __forceinline__ u64 ld_h64(const u64* p) {
  return __hip_atomic_load(p, __ATOMIC_RELAXED, __HIP_MEMORY_SCOPE_AGENT);
}
static __device__ __forceinline__ void st_h64(uint16_t* p, u64 v) {
  __hip_atomic_store((u64*)p, v, __ATOMIC_RELAXED, __HIP_MEMORY_SCOPE_AGENT);
}
// poll 8 consecutive u64 words until none equals the sentinel
static __device__ __forceinline__ void poll8(const u64* p, u64* o) {
  for (;;) {
    bool ok = true;
    #pragma unroll
    for (int i = 0; i < 8; ++i) { o[i] = ld_h64(p + i); ok &= (o[i] != SENT); }
    if (ok) break;
    __builtin_amdgcn_s_sleep(1);
  }
}

#define H 256
#define FH 1024
#define BATCH 32
#define TSEQ 512
#define DSTEPS 64
#define ERING 8          // encoder h-slot ring depth

// =====================================================================
// Phase A GEMM (round-2 form)
// =====================================================================
__global__ __launch_bounds__(256) void gemm_xw(
    const float* __restrict__ A, const float* __restrict__ W,
    const float* __restrict__ bias, void* __restrict__ Cout, int out_f32)
{
  const int K = 1024, N = 1024;
  __shared__ uint16_t Ah[64 * 40], Al[64 * 40];
  __shared__ uint16_t Wh[64 * 40], Wl[64 * 40];
  const int m0 = blockIdx.x * 64;
  const int n0 = blockIdx.y * 64;
  const int tid = threadIdx.x;
  const int lane = tid & 63, w = tid >> 6;
  const int wm = w & 1, wn = w >> 1;
  const int l15 = lane & 15, q4 = lane >> 4;
  const int ldrow = tid >> 2, ldk = (tid & 3) * 8;

  floatx4 acc[2][2];
  for (int i = 0; i < 2; ++i) for (int j = 0; j < 2; ++j) acc[i][j] = (floatx4){0.f,0.f,0.f,0.f};

  for (int kb = 0; kb < K; kb += 32) {
    float aa[8], ww[8];
    {
      const float4* ap = (const float4*)(A + (size_t)(m0 + ldrow) * K + kb + ldk);
      const float4* wp = (const float4*)(W + (size_t)(n0 + ldrow) * K + kb + ldk);
      *(float4*)(aa) = ap[0]; *(float4*)(aa + 4) = ap[1];
      *(float4*)(ww) = wp[0]; *(float4*)(ww + 4) = wp[1];
    }
    short8 ah, al, wh, wl;
    #pragma unroll
    for (int i = 0; i < 8; ++i) {
      uint16_t h = f2b(aa[i]); ah[i] = (short)h; al[i] = (short)f2b(aa[i] - b2f(h));
      uint16_t g = f2b(ww[i]); wh[i] = (short)g; wl[i] = (short)f2b(ww[i] - b2f(g));
    }
    __syncthreads();
    *(short8*)(Ah + ldrow * 40 + ldk) = ah;
    *(short8*)(Al + ldrow * 40 + ldk) = al;
    *(short8*)(Wh + ldrow * 40 + ldk) = wh;
    *(short8*)(Wl + ldrow * 40 + ldk) = wl;
    __syncthreads();
    short8 afh[2], afl[2], bfh[2], bfl[2];
    #pragma unroll
    for (int mt = 0; mt < 2; ++mt) {
      afh[mt] = *(const short8*)(Ah + (wm * 32 + mt * 16 + l15) * 40 + q4 * 8);
      afl[mt] = *(const short8*)(Al + (wm * 32 + mt * 16 + l15) * 40 + q4 * 8);
    }
    #pragma unroll
    for (int nt = 0; nt < 2; ++nt) {
      bfh[nt] = *(const short8*)(Wh + (wn * 32 + nt * 16 + l15) * 40 + q4 * 8);
      bfl[nt] = *(const short8*)(Wl + (wn * 32 + nt * 16 + l15) * 40 + q4 * 8);
    }
    #pragma unroll
    for (int mt = 0; mt < 2; ++mt)
      #pragma unroll
      for (int nt = 0; nt < 2; ++nt) {
        acc[mt][nt] = mfma16(afh[mt], bfh[nt], acc[mt][nt]);
        acc[mt][nt] = mfma16(afh[mt], bfl[nt], acc[mt][nt]);
        acc[mt][nt] = mfma16(afl[mt], bfh[nt], acc[mt][nt]);
      }
  }
  #pragma unroll
  for (int mt = 0; mt < 2; ++mt)
    #pragma unroll
    for (int nt = 0; nt < 2; ++nt) {
      const int col = n0 + wn * 32 + nt * 16 + l15;
      const float bv = bias[col];
      #pragma unroll
      for (int r = 0; r < 4; ++r) {
        const int row = m0 + wm * 32 + mt * 16 + q4 * 4 + r;
        const float v = acc[mt][nt][r] + bv;
        if (out_f32) ((float*)Cout)[(size_t)row * N + col] = v;
        else         ((uint16_t*)Cout)[(size_t)row * N + col] = f2b(v);
      }
    }
}

// =====================================================================
// Phase B: encoder recurrence. Grid = 16 WGs: d = blk>>3, q = blk&7.
// Round-5 sentinel protocol + Xg REGISTER PREFETCH: Xg loads for step s+1
// are issued after step s's poll, so the poll's vmcnt wait never drains
// HBM-latency Xg traffic — only its own 8 slot loads.
// =====================================================================
__global__ __launch_bounds__(256, 1) void enc_rnn(
    const void* __restrict__ XgF, const void* __restrict__ XgB, int xg_f32,
    const float* __restrict__ WhhF, const float* __restrict__ WhhB,
    uint16_t* __restrict__ hslots,    // [2 dir][ERING][32][256] bf16, poisoned
    uint16_t* __restrict__ hfin, float* __restrict__ cfin)
{
  const int d = blockIdx.x >> 3, q = blockIdx.x & 7;
  const void*  Xg  = d ? XgB : XgF;
  const float* Whh = d ? WhhB : WhhF;
  uint16_t* hsl = hslots + d * (ERING * BATCH * H);
  const int jOff = q * 32;
  const int tid = threadIdx.x, lane = tid & 63, w = tid >> 6;
  const int tt = w & 1, nt = w >> 1, l15 = lane & 15, q4 = lane >> 4;
  const int b = nt * 16 + l15;
  const int jg = jOff + tt * 16 + q4 * 4;

  __shared__ uint16_t hS[2][32 * 264];
  __shared__ float    xgS[2][32 * 132];

  short8 Af[4][8];
  #pragma unroll
  for (int g = 0; g < 4; ++g) {
    const int grow = g * H + jOff + tt * 16 + l15;
    #pragma unroll
    for (int ks = 0; ks < 8; ++ks)
      Af[g][ks] = cvt8(Whh + (size_t)grow * H + ks * 32 + q4 * 8);
  }
  for (int i = tid; i < 32 * 264; i += 256) hS[0][i] = 0;   // h_0 = 0

  float cc[4] = {0.f, 0.f, 0.f, 0.f};
  union HV { uint16_t u16[4]; u64 v; } hv; hv.v = 0ull;
  const int rb = tid >> 3, seg = tid & 7;
  const int cp = seg * 16;
  const int gge = cp >> 5, jj = cp & 31;

  // Xg slice loader for step s (t depends on direction)
  float xv[16], xn[16];
  #define LOAD_XG(dst, s_) do {                                              \
    const int t_ = d ? (TSEQ - 1 - (s_)) : (s_);                             \
    const size_t base_ = (size_t)(t_ * BATCH + rb) * FH + gge * H + jOff + jj;\
    if (xg_f32) {                                                            \
      const float4* xs_ = (const float4*)((const float*)Xg + base_);         \
      *(float4*)(dst) = xs_[0]; *(float4*)((dst) + 4) = xs_[1];              \
      *(float4*)((dst) + 8) = xs_[2]; *(float4*)((dst) + 12) = xs_[3];       \
    } else {                                                                 \
      const uint16_t* xs_ = (const uint16_t*)Xg + base_;                     \
      _Pragma("unroll")                                                      \
      for (int i_ = 0; i_ < 16; ++i_) (dst)[i_] = b2f(xs_[i_]);              \
    }                                                                        \
  } while (0)

  LOAD_XG(xv, 0);

  for (int s = 0; s < TSEQ; ++s) {
    const int p = s & 1;

    if (s > 0) {
      u64 tmp[8];
      const u64* ps = (const u64*)(hsl + ((s - 1) & (ERING - 1)) * (BATCH * H) + rb * H + seg * 32);
      poll8(ps, tmp);
      #pragma unroll
      for (int i = 0; i < 8; ++i)
        *(u64*)(hS[p] + rb * 264 + seg * 32 + i * 4) = tmp[i];
    }
    if (s >= 2)   // re-poison own slice of slot s-2 for ring reuse
      st_h64(hsl + ((s - 2) & (ERING - 1)) * (BATCH * H) + b * H + jg, SENT);
    #pragma unroll
    for (int i = 0; i < 16; ++i) xgS[p][rb * 132 + cp + i] = xv[i];
    // prefetch next step's Xg (issued after the poll; consumed next iter)
    if (s + 1 < TSEQ) LOAD_XG(xn, s + 1);
    __syncthreads();

    floatx4 a0 = {0.f,0.f,0.f,0.f}, a1 = a0, a2 = a0, a3 = a0;
    #pragma unroll
    for (int ks = 0; ks < 8; ++ks) {
      short8 bfv = *(const short8*)(hS[p] + b * 264 + ks * 32 + q4 * 8);
      a0 = mfma16(Af[0][ks], bfv, a0);
      a1 = mfma16(Af[1][ks], bfv, a1);
      a2 = mfma16(Af[2][ks], bfv, a2);
      a3 = mfma16(Af[3][ks], bfv, a3);
    }
    #pragma unroll
    for (int r = 0; r < 4; ++r) {
      const int jl = tt * 16 + q4 * 4 + r;
      const float gi = a0[r] + xgS[p][b * 132 +      jl];
      const float gf = a1[r] + xgS[p][b * 132 + 32 + jl];
      const float gc = a2[r] + xgS[p][b * 132 + 64 + jl];
      const float go = a3[r] + xgS[p][b * 132 + 96 + jl];
      const float cn2 = sigm(gf) * cc[r] + sigm(gi) * tanh_f(gc);
      cc[r] = cn2;
      hv.u16[r] = f2b(sigm(go) * tanh_f(cn2));
    }
    st_h64(hsl + (s & (ERING - 1)) * (BATCH * H) + b * H + jg, hv.v);
    #pragma unroll
    for (int i = 0; i < 16; ++i) xv[i] = xn[i];
  }
  #pragma unroll
  for (int r = 0; r < 4; ++r) {
    hfin[d * (BATCH * H) + b * H + jg + r] = hv.u16[r];   // kernel boundary
    cfin[d * (BATCH * H) + b * H + jg + r] = cc[r];
  }
  #undef LOAD_XG
}

// =====================================================================
// Phase C: decoder, 2 layers x 64 steps. Grid = 16 WGs: L = blk>>3, q = blk&7.
// Write-once per-step slots, data-is-the-flag. Both dependencies (own-layer
// h and cross-layer x) polled in ONE merged loop (saves a round trip/step).
// =====================================================================
__global__ __launch_bounds__(256, 1) void dec_rnn(
    const float* __restrict__ Wih0, const float* __restrict__ Whh0, const float* __restrict__ bb0,
    const float* __restrict__ Wih1, const float* __restrict__ Whh1, const float* __restrict__ bb1,
    const uint16_t* __restrict__ hfin, const float* __restrict__ cfin,
    uint16_t* __restrict__ h0slots,  // [64][32][256] bf16, poisoned
    uint16_t* __restrict__ h1slots,  // [64][32][256] bf16, poisoned
    float*    __restrict__ h1f)      // [64][32][256] f32 (plain)
{
  const int L = blockIdx.x >> 3, q = blockIdx.x & 7;
  const float* Wih = L ? Wih1 : Wih0;
  const float* Whh = L ? Whh1 : Whh0;
  const float* bs  = L ? bb1 : bb0;
  const int jOff = q * 32;
  const int tid = threadIdx.x, lane = tid & 63, w = tid >> 6;
  const int tt = w & 1, nt = w >> 1, l15 = lane & 15, q4 = lane >> 4;
  const int b = nt * 16 + l15;
  const int jg = jOff + tt * 16 + q4 * 4;

  __shared__ uint16_t xhS[2][32 * 528];

  short8 Af[4][16];
  #pragma unroll
  for (int g = 0; g < 4; ++g) {
    const int grow = g * H + jOff + tt * 16 + l15;
    #pragma unroll
    for (int ks = 0; ks < 8; ++ks) {
      Af[g][ks]     = cvt8(Wih + (size_t)grow * H + ks * 32 + q4 * 8);
      Af[g][8 + ks] = cvt8(Whh + (size_t)grow * H + ks * 32 + q4 * 8);
    }
  }
  float brg[4][4];
  #pragma unroll
  for (int g = 0; g < 4; ++g)
    #pragma unroll
    for (int r = 0; r < 4; ++r)
      brg[g][r] = bs[g * H + jOff + tt * 16 + q4 * 4 + r];

  float cc[4];
  #pragma unroll
  for (int r = 0; r < 4; ++r) cc[r] = cfin[L * (BATCH * H) + b * H + jg + r];

  const int rb = tid >> 3, seg = tid & 7;
  const size_t off = (size_t)rb * H + seg * 32;
  union HV { uint16_t u16[4]; u64 v; } hv; hv.v = 0ull;

  for (int t = 0; t < DSTEPS; ++t) {
    const int p = t & 1;
    u64 tx[8], th[8];
    const u64* pa = nullptr;   // own-layer previous h
    const u64* pb = nullptr;   // cross-layer x
    if (t == 0) {
      const u64* ph = (const u64*)(hfin + L * (BATCH * H) + off);
      for (int i = 0; i < 8; ++i) th[i] = ph[i];       // plain, kernel boundary
    } else {
      pa = (const u64*)(((L ? h1slots : h0slots) + (size_t)(t - 1) * (BATCH * H)) + off);
    }
    if (L == 0) {
      if (t == 0) {
        for (int i = 0; i < 8; ++i) tx[i] = 0ull;
      } else {
        pb = (const u64*)(h1slots + (size_t)(t - 1) * (BATCH * H) + off);
      }
    } else {
      pb = (const u64*)(h0slots + (size_t)t * (BATCH * H) + off);
    }
    if (pa || pb) {
      if (pa) { for (int i = 0; i < 8; ++i) th[i] = SENT; }
      if (pb) { for (int i = 0; i < 8; ++i) tx[i] = SENT; }
      for (;;) {
        bool ok = true;
        if (pa) {
          #pragma unroll
          for (int i = 0; i < 8; ++i) {
            if (th[i] == SENT) th[i] = ld_h64(pa + i);
            ok &= (th[i] != SENT);
          }
        }
        if (pb) {
          #pragma unroll
          for (int i = 0; i < 8; ++i) {
            if (tx[i] == SENT) tx[i] = ld_h64(pb + i);
            ok &= (tx[i] != SENT);
          }
        }
        if (ok) break;
        __builtin_amdgcn_s_sleep(1);
      }
    }
    #pragma unroll
    for (int i = 0; i < 8; ++i) {
      *(u64*)(xhS[p] + rb * 528 + seg * 32 + i * 4) = tx[i];
      *(u64*)(xhS[p] + rb * 528 + 256 + seg * 32 + i * 4) = th[i];
    }
    __syncthreads();

    floatx4 a0 = {0.f,0.f,0.f,0.f}, a1 = a0, a2 = a0, a3 = a0;
    #pragma unroll
    for (int ks = 0; ks < 16; ++ks) {
      short8 bfv = *(const short8*)(xhS[p] + b * 528 + ks * 32 + q4 * 8);
      a0 = mfma16(Af[0][ks], bfv, a0);
      a1 = mfma16(Af[1][ks], bfv, a1);
      a2 = mfma16(Af[2][ks], bfv, a2);
      a3 = mfma16(Af[3][ks], bfv, a3);
    }
    float hval[4];
    #pragma unroll
    for (int r = 0; r < 4; ++r) {
      const float gi = a0[r] + brg[0][r];
      const float gf = a1[r] + brg[1][r];
      const float gc = a2[r] + brg[2][r];
      const float go = a3[r] + brg[3][r];
      const float cn2 = sigm(gf) * cc[r] + sigm(gi) * tanh_f(gc);
      cc[r] = cn2;
      hval[r] = sigm(go) * tanh_f(cn2);
      hv.u16[r] = f2b(hval[r]);
    }
    st_h64((L ? h1slots : h0slots) + (size_t)t * (BATCH * H) + b * H + jg, hv.v);
    if (L == 1) {
      float* df = h1f + (size_t)t * (BATCH * H) + b * H + jg;
      #pragma unroll
      for (int r = 0; r < 4; ++r) df[r] = hval[r];
    }
  }
}

// =====================================================================
// Phase D
// =====================================================================
__global__ __launch_bounds__(256) void out_proj(
    const float* __restrict__ h1f, const float* __restrict__ linW,
    const float* __restrict__ linb, float* __restrict__ out)
{
  const int idx = blockIdx.x * 256 + threadIdx.x;
  if (idx >= DSTEPS * BATCH * 3) return;
  const int v = idx % 3;
  const int tb = idx / 3;
  const float* hrow = h1f + (size_t)tb * H;
  const float* wrow = linW + (size_t)v * H;
  float s = linb[v];
  for (int k = 0; k < H; ++k) s += hrow[k] * wrow[k];
  out[idx] = s;
}

// =====================================================================
extern "C" void kernel_launch(void* const* d_in, const int* in_sizes, int n_in,
                              void* d_out, int out_size, void* d_ws, size_t ws_size,
                              hipStream_t stream) {
  (void)in_sizes; (void)n_in; (void)out_size;
  const float* cnn   = (const float*)d_in[0];
  const float* WihF  = (const float*)d_in[1];
  const float* WhhF  = (const float*)d_in[2];
  const float* bF    = (const float*)d_in[3];
  const float* WihB  = (const float*)d_in[4];
  const float* WhhB  = (const float*)d_in[5];
  const float* bB    = (const float*)d_in[6];
  const float* Wih0  = (const float*)d_in[7];
  const float* Whh0  = (const float*)d_in[8];
  const float* b0    = (const float*)d_in[9];
  const float* Wih1  = (const float*)d_in[10];
  const float* Whh1  = (const float*)d_in[11];
  const float* b1    = (const float*)d_in[12];
  const float* linW  = (const float*)d_in[13];
  const float* linb  = (const float*)d_in[14];

  const size_t XG_ELEMS = (size_t)TSEQ * BATCH * FH;   // 16 Mi elems / dir
  // small region: hslotsE 262144 | h0slots 1 MB | h1slots 1 MB | hfin 32K | cfin 64K
  const size_t SMALL = 2457600;
  const int xg_f32 = (ws_size >= 2 * XG_ELEMS * 4 + SMALL) ? 1 : 0;
  const size_t S = XG_ELEMS * (xg_f32 ? 4 : 2);

  uint8_t* ws = (uint8_t*)d_ws;
  void*     XgF    = (void*)(ws);
  void*     XgB    = (void*)(ws + S);
  float*    h1f    = (float*)(ws + S);                 // overlaps XgB: dead after enc
  uint8_t*  base   = ws + 2 * S;
  uint16_t* hslotsE = (uint16_t*)(base);               // 2*8*8192*2   = 262144
  uint16_t* h0slots = (uint16_t*)(base + 262144);      // 64*8192*2    = 1048576
  uint16_t* h1slots = (uint16_t*)(base + 1310720);     // 1048576  (poison end 2359296)
  uint16_t* hfin    = (uint16_t*)(base + 2359296);     // 32768
  float*    cfin    = (float*)(base + 2392064);        // 65536 (end 2457600)

  // sentinel-poison all exchange slots (required every launch, incl. replays)
  (void)hipMemsetAsync(base, 0xAA, 2359296, stream);

  gemm_xw<<<dim3(256, 16), 256, 0, stream>>>(cnn, WihF, bF, XgF, xg_f32);
  gemm_xw<<<dim3(256, 16), 256, 0, stream>>>(cnn, WihB, bB, XgB, xg_f32);
  enc_rnn<<<16, 256, 0, stream>>>(XgF, XgB, xg_f32, WhhF, WhhB,
                                  hslotsE, hfin, cfin);
  dec_rnn<<<16, 256, 0, stream>>>(Wih0, Whh0, b0, Wih1, Whh1, b1,
                                  hfin, cfin, h0slots, h1slots, h1f);
  out_proj<<<24, 256, 0, stream>>>(h1f, linW, linb, (float*)d_out);
}